// Round 3
// baseline (452.726 us; speedup 1.0000x reference)
//
#include <hip/hip_runtime.h>

typedef unsigned short u16;
typedef __bf16 bf16_t;
typedef bf16_t bf16x8 __attribute__((ext_vector_type(8)));
typedef float floatx4 __attribute__((ext_vector_type(4)));

static constexpr float kScale = 0.014731391274719741f;    // 1/sqrt(512*9)
static constexpr float kScale2 = 2.1701388888888894e-4f;  // 1/(512*9)
static constexpr float kLinScale = 0.044194173824159216f; // 1/sqrt(512)

__device__ __forceinline__ u16 f2bf(float f) {
  unsigned u = __float_as_uint(f);
  u += 0x7FFFu + ((u >> 16) & 1u);
  return (u16)(u >> 16);
}

// async 16B global->LDS; LDS dst semantics: wave-uniform base + lane*16
#define GLD16(g, l)                                                        \
  __builtin_amdgcn_global_load_lds(                                        \
      (const __attribute__((address_space(1))) unsigned int*)(g),          \
      (__attribute__((address_space(3))) unsigned int*)(l), 16, 0, 0)

// ---------------------------------------------------------------------------
// s[b,c] = sum_s style[b,s]*modw[c,s]*lin_scale + bias[c]
__global__ __launch_bounds__(256) void k_style(const float* __restrict__ style,
                                               const float* __restrict__ modw,
                                               const float* __restrict__ modb,
                                               float* __restrict__ s_buf) {
  int tid = threadIdx.x, lane = tid & 63, wv = tid >> 6;
  int idx = blockIdx.x * 4 + wv; // [0,4096)
  int b = idx >> 9, c = idx & 511;
  const float* st = style + b * 512;
  const float* mw = modw + (size_t)c * 512;
  float s = 0.f;
#pragma unroll
  for (int i = 0; i < 8; ++i) s += st[lane + i * 64] * mw[lane + i * 64];
#pragma unroll
  for (int off = 32; off; off >>= 1) s += __shfl_xor(s, off);
  if (lane == 0) s_buf[idx] = s * kLinScale + modb[c];
}

// ---------------------------------------------------------------------------
// ssq[o,c] = sum_tap w[o,c,tap]^2   (weight read once, 9.4 MB)
__global__ __launch_bounds__(256) void k_ssq(const float* __restrict__ weight,
                                             float* __restrict__ ssq) {
  int e = blockIdx.x * 256 + threadIdx.x; // [0, 262144)
  const float* wp = weight + (size_t)e * 9;
  float ss = 0.f;
#pragma unroll
  for (int t = 0; t < 9; ++t) ss += wp[t] * wp[t];
  ssq[e] = ss;
}

// ---------------------------------------------------------------------------
// demod[b,o] = rsqrt( kScale^2 * sum_c ssq[o,c]*s[b,c]^2 + eps )
__global__ __launch_bounds__(256) void k_demod2(const float* __restrict__ ssq,
                                                const float* __restrict__ s_buf,
                                                float* __restrict__ demod_buf) {
  int tid = threadIdx.x, lane = tid & 63, wv = tid >> 6;
  int idx = blockIdx.x * 4 + wv; // [0,4096)
  int b = idx >> 9, o = idx & 511;
  const float* sq = ssq + (size_t)o * 512;
  const float* srow = s_buf + b * 512;
  float ss = 0.f;
#pragma unroll
  for (int i = 0; i < 8; ++i) {
    float s = srow[lane + i * 64];
    ss += sq[lane + i * 64] * s * s;
  }
#pragma unroll
  for (int off = 32; off; off >>= 1) ss += __shfl_xor(ss, off);
  if (lane == 0) demod_buf[idx] = rsqrtf(ss * kScale2 + 1e-8f);
}

// ---------------------------------------------------------------------------
// NCHW f32 -> NHWC bf16, u32-pair coalesced writes. Padded LDS (65) kills
// the stride-64 bank conflict on the read phase.
__global__ __launch_bounds__(256) void k_transpose(const float* __restrict__ in,
                                                   unsigned* __restrict__ in_t32) {
  __shared__ u16 tile[64 * 65];
  int tid = threadIdx.x;
  int c0 = blockIdx.x * 64, y = blockIdx.y, b = blockIdx.z;
  const float* src = in + ((size_t)(b * 512 + c0) * 4096) + y * 64;
#pragma unroll
  for (int it = 0; it < 16; ++it) {
    int idx = it * 256 + tid;
    int cl = idx >> 6, x = idx & 63;
    tile[cl * 65 + x] = f2bf(src[(size_t)cl * 4096 + x]);
  }
  __syncthreads();
  unsigned* dst = in_t32 + ((size_t)(b * 64 + y) * 64) * 256 + (c0 >> 1);
#pragma unroll
  for (int it = 0; it < 8; ++it) {
    int flat = it * 256 + tid; // [0,2048)
    int cl2 = flat & 31, x = flat >> 5;
    unsigned lo = tile[(2 * cl2) * 65 + x];
    unsigned hi = tile[(2 * cl2 + 1) * 65 + x];
    dst[(size_t)x * 256 + cl2] = lo | (hi << 16);
  }
}

// ---------------------------------------------------------------------------
// Build w_t fragment tiles, contiguous global reads (1152 B per o-row).
// w_t layout [b][tap][ct][ot][512], pos = (m + 16*(k>>3))*8 + (k&7).
__global__ __launch_bounds__(256) void k_weights(const float* __restrict__ weight,
                                                 const float* __restrict__ s_buf,
                                                 const float* __restrict__ demod_buf,
                                                 unsigned* __restrict__ wt32) {
  __shared__ u16 tiles[9][512];
  int tid = threadIdx.x;
  int ct = blockIdx.x, ot = blockIdx.y, b = blockIdx.z;
  int o0 = ot * 16, c0 = ct * 32;
#pragma unroll
  for (int i = 0; i < 18; ++i) {
    int flat = i * 256 + tid;         // [0,4608) = o_l*288 + c_l*9 + tap
    int t9 = flat / 9;
    int tap = flat - t9 * 9;
    int o_l = t9 >> 5, c_l = t9 & 31;
    float w = weight[((size_t)(o0 + o_l) * 512 + c0 + c_l) * 9 + tap];
    float f = kScale * s_buf[b * 512 + c0 + c_l] * demod_buf[b * 512 + o0 + o_l];
    int pos = ((o_l + ((c_l >> 3) << 4)) << 3) + (c_l & 7);
    tiles[tap][pos] = f2bf(w * f);
  }
  __syncthreads();
  const unsigned* tl = (const unsigned*)tiles;
#pragma unroll
  for (int tap = 0; tap < 9; ++tap)
    wt32[(size_t)(((b * 9 + tap) * 16 + ct) * 32 + ot) * 256 + tid] = tl[tap * 256 + tid];
}

// ---------------------------------------------------------------------------
// Implicit-GEMM conv. Grid (nt=16, mt=4, b=8) = 512 blocks (2/CU).
// Block: 128 O x 256 px (4 rows). Per dx: 12 ds_read serve 32 MFMA/wave.
__global__ __launch_bounds__(256, 2) void k_conv(const u16* __restrict__ in_t,
                                                 const u16* __restrict__ w_t,
                                                 float* __restrict__ out) {
  __shared__ char smem[49152]; // A: [0,24576) 3 taps x 8KB ; B: [24576,49152) 384 slots x 64B
  char* As = smem;
  char* Bs = smem + 24576;
  const int tid = threadIdx.x;
  const int lane = tid & 63;
  const int wv = tid >> 6;
  const int wm = wv >> 1, wn = wv & 1;
  const int quad = lane >> 4, m16 = lane & 15;
  const int nt = blockIdx.x, mt = blockIdx.y, b = blockIdx.z;
  const int y0 = nt * 4;

  floatx4 acc[4][8];
#pragma unroll
  for (int i = 0; i < 4; ++i)
#pragma unroll
    for (int j = 0; j < 8; ++j) acc[i][j] = (floatx4){0.f, 0.f, 0.f, 0.f};

  for (int ct = 0; ct < 16; ++ct) {
    const int c0 = ct * 32;
    // stage B: rows y0-1..y0+4 (6 rows), 64 x, 32 ch; chunk q at s*64+((q^(x&3))*16)
#pragma unroll
    for (int r = 0; r < 6; ++r) {
      const int ci = r * 256 + tid;
      const int s = ci >> 2, qi = ci & 3;
      const int x = s & 63;
      const int y = y0 - 1 + r; // block-uniform per r
      const int qd = qi ^ (x & 3);
      char* lbase = Bs + r * 4096 + wv * 1024;
      if ((unsigned)y < 64u) {
        const u16* g = in_t + (((size_t)(b * 64 + y) * 64 + x) * 512 + c0 + qd * 8);
        GLD16(g, lbase);
      } else {
        *(uint4*)(Bs + ci * 16) = make_uint4(0u, 0u, 0u, 0u);
      }
    }
    for (int dy = 0; dy < 3; ++dy) {
      // stage A: taps dy*3+{0,1,2}
#pragma unroll
      for (int r6 = 0; r6 < 6; ++r6) {
        const int sec = r6 >> 1, half = r6 & 1;
        const int tap = dy * 3 + sec;
        const u16* g = w_t + ((size_t)((b * 9 + tap) * 16 + ct) << 14) +
                       mt * 4096 + half * 2048 + wv * 512 + lane * 8;
        char* lbase = As + sec * 8192 + half * 4096 + wv * 1024;
        GLD16(g, lbase);
      }
      __syncthreads();
#pragma unroll
      for (int dx = 0; dx < 3; ++dx) {
        bf16x8 af[4];
#pragma unroll
        for (int ms = 0; ms < 4; ++ms)
          af[ms] = *(const bf16x8*)(As + dx * 8192 + (wm * 4 + ms) * 1024 + lane * 16);
#pragma unroll
        for (int ns = 0; ns < 8; ++ns) {
          const int nl = wn * 128 + ns * 16 + m16;
          const int ly = nl >> 6, lx = nl & 63;
          const int sx = lx + dx - 1;
          bf16x8 bv;
          if ((unsigned)sx < 64u) {
            const int s = (ly + dy) * 64 + sx;
            bv = *(const bf16x8*)(Bs + s * 64 + ((quad ^ (sx & 3)) << 4));
          } else {
#pragma unroll
            for (int j = 0; j < 8; ++j) bv[j] = (bf16_t)0.f;
          }
#pragma unroll
          for (int ms = 0; ms < 4; ++ms)
            acc[ms][ns] =
                __builtin_amdgcn_mfma_f32_16x16x32_bf16(af[ms], bv, acc[ms][ns], 0, 0, 0);
        }
      }
      __syncthreads();
    }
  }
  // epilogue: D[m=quad*4+r][n=lane&15], f32 out
  const int ob = mt * 128 + wm * 64;
  const int nb = nt * 256 + wn * 128;
#pragma unroll
  for (int ms = 0; ms < 4; ++ms)
#pragma unroll
    for (int ns = 0; ns < 8; ++ns) {
      const int n = nb + ns * 16 + m16;
#pragma unroll
      for (int r = 0; r < 4; ++r) {
        const int o = ob + ms * 16 + quad * 4 + r;
        out[((size_t)(b * 512 + o) << 12) + n] = acc[ms][ns][r];
      }
    }
}

// ---------------------------------------------------------------------------
extern "C" void kernel_launch(void* const* d_in, const int* in_sizes, int n_in,
                              void* d_out, int out_size, void* d_ws, size_t ws_size,
                              hipStream_t stream) {
  const float* input = (const float*)d_in[0];   // [8,512,64,64] f32
  const float* style = (const float*)d_in[1];   // [8,512] f32
  const float* weight = (const float*)d_in[2];  // [1,512,512,3,3] f32
  const float* modw = (const float*)d_in[3];    // [512,512] f32
  const float* modb = (const float*)d_in[4];    // [512] f32
  float* out = (float*)d_out;                   // [8,512,64,64] f32
  char* ws = (char*)d_ws;
  float* s_buf = (float*)ws;                             // 16 KB
  float* demod_buf = (float*)(ws + 16384);               // 16 KB
  float* ssq = (float*)(ws + 32768);                     // 1 MB
  u16* in_t = (u16*)(ws + 32768 + 1048576);              // NHWC bf16, 33.5 MB
  u16* w_t = (u16*)(ws + 32768 + 1048576 + 33554432);    // frag bf16, 37.7 MB

  k_style<<<dim3(1024), dim3(256), 0, stream>>>(style, modw, modb, s_buf);
  k_ssq<<<dim3(1024), dim3(256), 0, stream>>>(weight, ssq);
  k_demod2<<<dim3(1024), dim3(256), 0, stream>>>(ssq, s_buf, demod_buf);
  k_transpose<<<dim3(8, 64, 8), dim3(256), 0, stream>>>(input, (unsigned*)in_t);
  k_weights<<<dim3(16, 32, 8), dim3(256), 0, stream>>>(weight, s_buf, demod_buf,
                                                       (unsigned*)w_t);
  k_conv<<<dim3(16, 4, 8), dim3(256), 0, stream>>>(in_t, w_t, out);
}

// Round 4
// 254.803 us; speedup vs baseline: 1.7768x; 1.7768x over previous
//
#include <hip/hip_runtime.h>

typedef unsigned short u16;
typedef __bf16 bf16_t;
typedef bf16_t bf16x8 __attribute__((ext_vector_type(8)));
typedef float floatx4 __attribute__((ext_vector_type(4)));

static constexpr float kScale = 0.014731391274719741f;    // 1/sqrt(512*9)
static constexpr float kScale2 = 2.1701388888888894e-4f;  // 1/(512*9)
static constexpr float kLinScale = 0.044194173824159216f; // 1/sqrt(512)

__device__ __forceinline__ u16 f2bf(float f) {
  unsigned u = __float_as_uint(f);
  u += 0x7FFFu + ((u >> 16) & 1u);
  return (u16)(u >> 16);
}

// async 16B global->LDS; LDS dst semantics: wave-uniform base + lane*16
#define GLD16(g, l)                                                        \
  __builtin_amdgcn_global_load_lds(                                        \
      (const __attribute__((address_space(1))) unsigned int*)(g),          \
      (__attribute__((address_space(3))) unsigned int*)(l), 16, 0, 0)

// ---------------------------------------------------------------------------
// Fused prep: blocks [0,1024): s[b,c] = style.modw^T*lin + bias
//             blocks [1024,2048): ssq[o,c] = sum_tap w^2
__global__ __launch_bounds__(256) void k_prep1(const float* __restrict__ style,
                                               const float* __restrict__ modw,
                                               const float* __restrict__ modb,
                                               const float* __restrict__ weight,
                                               float* __restrict__ s_buf,
                                               float* __restrict__ ssq) {
  int tid = threadIdx.x;
  if (blockIdx.x < 1024) {
    int lane = tid & 63, wv = tid >> 6;
    int idx = blockIdx.x * 4 + wv; // [0,4096)
    int b = idx >> 9, c = idx & 511;
    const float* st = style + b * 512;
    const float* mw = modw + (size_t)c * 512;
    float s = 0.f;
#pragma unroll
    for (int i = 0; i < 8; ++i) s += st[lane + i * 64] * mw[lane + i * 64];
#pragma unroll
    for (int off = 32; off; off >>= 1) s += __shfl_xor(s, off);
    if (lane == 0) s_buf[idx] = s * kLinScale + modb[c];
  } else {
    int e = (blockIdx.x - 1024) * 256 + tid; // [0, 262144)
    const float* wp = weight + (size_t)e * 9;
    float ss = 0.f;
#pragma unroll
    for (int t = 0; t < 9; ++t) ss += wp[t] * wp[t];
    ssq[e] = ss;
  }
}

// ---------------------------------------------------------------------------
// demod[b,o] = rsqrt( kScale^2 * sum_c ssq[o,c]*s[b,c]^2 + eps )
__global__ __launch_bounds__(256) void k_demod2(const float* __restrict__ ssq,
                                                const float* __restrict__ s_buf,
                                                float* __restrict__ demod_buf) {
  int tid = threadIdx.x, lane = tid & 63, wv = tid >> 6;
  int idx = blockIdx.x * 4 + wv; // [0,4096)
  int b = idx >> 9, o = idx & 511;
  const float* sq = ssq + (size_t)o * 512;
  const float* srow = s_buf + b * 512;
  float ss = 0.f;
#pragma unroll
  for (int i = 0; i < 8; ++i) {
    float s = srow[lane + i * 64];
    ss += sq[lane + i * 64] * s * s;
  }
#pragma unroll
  for (int off = 32; off; off >>= 1) ss += __shfl_xor(ss, off);
  if (lane == 0) demod_buf[idx] = rsqrtf(ss * kScale2 + 1e-8f);
}

// ---------------------------------------------------------------------------
// NCHW f32 -> NHWC bf16 with fused per-channel modulation:
// in_t[b,y,x,c] = bf16( in[b,c,y,x] * s[b,c] )
__global__ __launch_bounds__(256) void k_transpose(const float* __restrict__ in,
                                                   const float* __restrict__ s_buf,
                                                   unsigned* __restrict__ in_t32) {
  __shared__ u16 tile[64 * 65];
  int tid = threadIdx.x;
  int c0 = blockIdx.x * 64, y = blockIdx.y, b = blockIdx.z;
  const float* src = in + ((size_t)(b * 512 + c0) * 4096) + y * 64;
  const float* srow = s_buf + b * 512 + c0;
#pragma unroll
  for (int it = 0; it < 16; ++it) {
    int idx = it * 256 + tid;
    int cl = idx >> 6, x = idx & 63;
    tile[cl * 65 + x] = f2bf(src[(size_t)cl * 4096 + x] * srow[cl]);
  }
  __syncthreads();
  unsigned* dst = in_t32 + ((size_t)(b * 64 + y) * 64) * 256 + (c0 >> 1);
#pragma unroll
  for (int it = 0; it < 8; ++it) {
    int flat = it * 256 + tid; // [0,2048)
    int cl2 = flat & 31, x = flat >> 5;
    unsigned lo = tile[(2 * cl2) * 65 + x];
    unsigned hi = tile[(2 * cl2 + 1) * 65 + x];
    dst[(size_t)x * 256 + cl2] = lo | (hi << 16);
  }
}

// ---------------------------------------------------------------------------
// Batch-independent weight fragments: w_frag[tap][ct][ot][512] = kScale * w,
// pos = (o_l + 16*(c_l>>3))*8 + (c_l&7). Only 4.7 MB.
__global__ __launch_bounds__(256) void k_wfrag(const float* __restrict__ weight,
                                               unsigned* __restrict__ wt32) {
  __shared__ u16 tiles[9][512];
  int tid = threadIdx.x;
  int ct = blockIdx.x, ot = blockIdx.y;
  int o0 = ot * 16, c0 = ct * 32;
#pragma unroll
  for (int i = 0; i < 18; ++i) {
    int flat = i * 256 + tid;         // [0,4608) = o_l*288 + c_l*9 + tap
    int t9 = flat / 9;
    int tap = flat - t9 * 9;
    int o_l = t9 >> 5, c_l = t9 & 31;
    float w = weight[((size_t)(o0 + o_l) * 512 + c0 + c_l) * 9 + tap];
    int pos = ((o_l + ((c_l >> 3) << 4)) << 3) + (c_l & 7);
    tiles[tap][pos] = f2bf(w * kScale);
  }
  __syncthreads();
  const unsigned* tl = (const unsigned*)tiles;
#pragma unroll
  for (int tap = 0; tap < 9; ++tap)
    wt32[(size_t)((tap * 16 + ct) * 32 + ot) * 256 + tid] = tl[tap * 256 + tid];
}

// ---------------------------------------------------------------------------
// Implicit-GEMM conv with shared weights. Grid (nt=32, mt=4, b=8) = 1024.
// 128 O x 128 px (2 rows). Epilogue scales by demod[b,o].
__global__ __launch_bounds__(256) void k_conv(const u16* __restrict__ in_t,
                                              const u16* __restrict__ w_t,
                                              const float* __restrict__ demod_buf,
                                              float* __restrict__ out) {
  __shared__ char smem[40960]; // A: [0,24576) 3 taps x 8KB ; B: [24576,40960)
  char* As = smem;
  char* Bs = smem + 24576;
  const int tid = threadIdx.x;
  const int lane = tid & 63;
  const int wv = tid >> 6;
  const int wm = wv >> 1, wn = wv & 1;
  const int quad = lane >> 4, m16 = lane & 15;
  const int nt = blockIdx.x, mt = blockIdx.y, b = blockIdx.z;
  const int y0 = nt * 2;

  floatx4 acc[4][4];
#pragma unroll
  for (int i = 0; i < 4; ++i)
#pragma unroll
    for (int j = 0; j < 4; ++j) acc[i][j] = (floatx4){0.f, 0.f, 0.f, 0.f};

  for (int ct = 0; ct < 16; ++ct) {
    const int c0 = ct * 32;
    // stage B: rows y0-1..y0+2, 64 x, 32 ch; chunk q at s*64+((q^(x&3))*16)
#pragma unroll
    for (int r = 0; r < 4; ++r) {
      const int ci = r * 256 + tid;
      const int s = ci >> 2, qi = ci & 3;
      const int x = s & 63;
      const int y = y0 - 1 + r; // block-uniform
      const int qd = qi ^ (x & 3);
      char* lbase = Bs + (r * 4 + wv) * 1024;
      if ((unsigned)y < 64u) {
        const u16* g = in_t + (((size_t)(b * 64 + y) * 64 + x) * 512 + c0 + qd * 8);
        GLD16(g, lbase);
      } else {
        *(uint4*)(Bs + ci * 16) = make_uint4(0u, 0u, 0u, 0u);
      }
    }
    for (int dy = 0; dy < 3; ++dy) {
      // stage A: taps dy*3+{0,1,2} (batch-independent!)
#pragma unroll
      for (int r6 = 0; r6 < 6; ++r6) {
        const int sec = r6 >> 1, half = r6 & 1;
        const int tap = dy * 3 + sec;
        const u16* g = w_t + ((size_t)(tap * 16 + ct) << 14) +
                       mt * 4096 + half * 2048 + wv * 512 + lane * 8;
        char* lbase = As + sec * 8192 + half * 4096 + wv * 1024;
        GLD16(g, lbase);
      }
      __syncthreads();
#pragma unroll
      for (int dx = 0; dx < 3; ++dx) {
        bf16x8 af[4];
#pragma unroll
        for (int ms = 0; ms < 4; ++ms)
          af[ms] = *(const bf16x8*)(As + dx * 8192 + (wm * 4 + ms) * 1024 + lane * 16);
#pragma unroll
        for (int ns = 0; ns < 4; ++ns) {
          const int nl = wn * 64 + ns * 16 + m16;
          const int ly = nl >> 6, lx = nl & 63;
          const int sx = lx + dx - 1;
          bf16x8 bv;
          if ((unsigned)sx < 64u) {
            const int s = (ly + dy) * 64 + sx;
            bv = *(const bf16x8*)(Bs + s * 64 + ((quad ^ (sx & 3)) << 4));
          } else {
#pragma unroll
            for (int j = 0; j < 8; ++j) bv[j] = (bf16_t)0.f;
          }
#pragma unroll
          for (int ms = 0; ms < 4; ++ms)
            acc[ms][ns] =
                __builtin_amdgcn_mfma_f32_16x16x32_bf16(af[ms], bv, acc[ms][ns], 0, 0, 0);
        }
      }
      __syncthreads();
    }
  }
  // epilogue: D[m=quad*4+r][n=lane&15], scale by demod[b,o], f32 out
  const int ob = mt * 128 + wm * 64;
  const int nb = nt * 128 + wn * 64;
#pragma unroll
  for (int ms = 0; ms < 4; ++ms)
#pragma unroll
    for (int ns = 0; ns < 4; ++ns) {
      const int n = nb + ns * 16 + m16;
#pragma unroll
      for (int r = 0; r < 4; ++r) {
        const int o = ob + ms * 16 + quad * 4 + r;
        float dm = demod_buf[b * 512 + o];
        out[((size_t)(b * 512 + o) << 12) + n] = acc[ms][ns][r] * dm;
      }
    }
}

// ---------------------------------------------------------------------------
extern "C" void kernel_launch(void* const* d_in, const int* in_sizes, int n_in,
                              void* d_out, int out_size, void* d_ws, size_t ws_size,
                              hipStream_t stream) {
  const float* input = (const float*)d_in[0];   // [8,512,64,64] f32
  const float* style = (const float*)d_in[1];   // [8,512] f32
  const float* weight = (const float*)d_in[2];  // [1,512,512,3,3] f32
  const float* modw = (const float*)d_in[3];    // [512,512] f32
  const float* modb = (const float*)d_in[4];    // [512] f32
  float* out = (float*)d_out;                   // [8,512,64,64] f32
  char* ws = (char*)d_ws;
  float* s_buf = (float*)ws;                             // 16 KB
  float* demod_buf = (float*)(ws + 16384);               // 16 KB
  float* ssq = (float*)(ws + 32768);                     // 1 MB
  u16* in_t = (u16*)(ws + 32768 + 1048576);              // NHWC bf16, 33.5 MB
  u16* w_t = (u16*)(ws + 32768 + 1048576 + 33554432);    // frag bf16, 4.7 MB

  k_prep1<<<dim3(2048), dim3(256), 0, stream>>>(style, modw, modb, weight, s_buf, ssq);
  k_demod2<<<dim3(1024), dim3(256), 0, stream>>>(ssq, s_buf, demod_buf);
  k_transpose<<<dim3(8, 64, 8), dim3(256), 0, stream>>>(input, s_buf, (unsigned*)in_t);
  k_wfrag<<<dim3(16, 32), dim3(256), 0, stream>>>(weight, (unsigned*)w_t);
  k_conv<<<dim3(32, 4, 8), dim3(256), 0, stream>>>(in_t, w_t, demod_buf, out);
}